// Round 23
// baseline (23.475 us; speedup 1.0000x reference)
//
#include <hip/hip_runtime.h>
#include <math.h>

#define N      8192
#define BLK    256
#define RPT    4                    // resident b-points per lane
#define G      (RPT / 2)            // packed pair-groups per lane (2)
#define BPW    (64 * RPT)           // 256 b-points per wave
#define NB     (N / BPW)            // 32 b-groups
#define NA     (N / 64)             // 128 a-tiles
#define GRID   ((NB * NA) / 4)      // 1024 blocks of 4 waves = 4 waves/SIMD
#define RBLK   1024
#define RGRID  8                    // widened reduce: 8 blocks

typedef float v2f __attribute__((ext_vector_type(2)));

// Full-wave rotate-by-1 on the VALU pipe (DPP wave_ror:1, ctrl 0x13C).
__device__ __forceinline__ float rot1(float x) {
    return __int_as_float(__builtin_amdgcn_mov_dpp(
        __float_as_int(x), 0x13C, 0xF, 0xF, false));
}

// ---------------------------------------------------- precompute + init ----
__global__ __launch_bounds__(BLK) void chamfer_prep_kernel(
        const float* __restrict__ tgt, const float* __restrict__ outp,
        float4* __restrict__ P, unsigned* __restrict__ dmin) {
    int i = blockIdx.x * BLK + (int)threadIdx.x;   // 0 .. 2N-1
    const float* src = (i < N) ? tgt : outp;
    int k = (i < N) ? i : (i - N);
    float x = src[3 * k + 0];
    float y = src[3 * k + 1];
    float z = src[3 * k + 2];
    P[i] = make_float4(x, y, z, fmaf(x, x, fmaf(y, y, z * z)));
    dmin[i] = 0x7F800000u;  // +inf
}

// ---------------------------------------------------------------- dist ----
// DPP systolic ring at RPT=4: 4096 wave-tasks -> 4 waves/SIMD (2x the TLP
// of the 22.9us RPT=8 best). R17's RPT=4 regression was bpermute-throughput
// (12cyc LDS pipe, doubled = +3.2us); DPP rotation is 2cyc VALU, doubling
// costs ~1.1us while latency-hiding capacity doubles on sweep stalls AND
// the fixed phases (prologue loads, commit). R21's LDS pre-combine kept:
// block's 4 waves share bt -> one global col commit per b-point per block.
__global__ __launch_bounds__(BLK) void chamfer_dist_kernel(
        const float4* __restrict__ P, unsigned* __restrict__ dmin) {
    __shared__ unsigned cm[BPW];               // block-combined col-mins (256)

    int tid  = (int)threadIdx.x;
    int lane = tid & 63;
    int W    = (int)blockIdx.x * 4 + (tid >> 6);   // global wave id
    int bt   = W >> 7;                             // b-group (shared by block)
    int at   = W & (NA - 1);                       // a-tile  (per wave)

    cm[tid] = 0x7F800000u;

    // resident B-points (output cloud), packed as point-pairs
    v2f bx2[G], by2[G], bz2[G], b22[G], ca2[G];
    #pragma unroll
    for (int g = 0; g < G; ++g) {
        float4 u = P[N + bt * BPW + (2 * g)     * 64 + lane];
        float4 v = P[N + bt * BPW + (2 * g + 1) * 64 + lane];
        bx2[g] = (v2f){u.x, v.x};
        by2[g] = (v2f){u.y, v.y};
        bz2[g] = (v2f){u.z, v.z};
        b22[g] = (v2f){u.w, v.w};
        ca2[g] = (v2f){__builtin_inff(), __builtin_inff()};
    }

    // own A-packet (target cloud)
    float4 a = P[at * 64 + lane];
    float px = -2.0f * a.x;
    float py = -2.0f * a.y;
    float pz = -2.0f * a.z;
    float pw = a.w;                       // a^2
    float pr = __builtin_inff();          // traveling row-min (d^2)

    __syncthreads();                      // cm initialized

    for (int s = 0; s < 64; ++s) {
        v2f px2 = {px, px}, py2 = {py, py}, pz2 = {pz, pz}, pw2 = {pw, pw};
        #pragma unroll
        for (int g = 0; g < G; ++g) {
            v2f t = __builtin_elementwise_fma(pz2, bz2[g], b22[g] + pw2);
            t     = __builtin_elementwise_fma(py2, by2[g], t);
            t     = __builtin_elementwise_fma(px2, bx2[g], t);   // full d^2
            pr     = fminf(fminf(pr, t.x), t.y);                 // v_min3
            ca2[g] = __builtin_elementwise_min(ca2[g], t);
        }
        px = rot1(px);
        py = rot1(py);
        pz = rot1(pz);
        pw = rot1(pw);
        pr = rot1(pr);
    }

    // packet home after 64 rotations: commit row-min (per-wave a-tile)
    atomicMin(&dmin[at * 64 + lane], __float_as_uint(fmaxf(pr, 0.0f)));

    // col-mins: LDS pre-combine across the block's 4 waves, then ONE
    // global commit per b-point per block.
    #pragma unroll
    for (int g = 0; g < G; ++g) {
        atomicMin(&cm[(2 * g)     * 64 + lane],
                  __float_as_uint(fmaxf(ca2[g].x, 0.0f)));
        atomicMin(&cm[(2 * g + 1) * 64 + lane],
                  __float_as_uint(fmaxf(ca2[g].y, 0.0f)));
    }
    __syncthreads();
    atomicMin(&dmin[N + bt * BPW + tid], cm[tid]);
}

// -------------------------------------------------------------- reduce ----
// Widened: 8 blocks x 1024 threads, each covering 1/8 of both dmin arrays.
__global__ __launch_bounds__(RBLK) void chamfer_reduce_kernel(
        const unsigned* __restrict__ dmin, float* __restrict__ bsum) {
    __shared__ float sh1[RBLK / 64], sh2[RBLK / 64];
    int t = (int)threadIdx.x;
    int chunk = N / 4 / RGRID;                     // uint4 elems per block
    int base = (int)blockIdx.x * chunk;
    float s1 = 0.0f, s2 = 0.0f;
    const uint4* da = (const uint4*)dmin;          // dist1 as uint4
    const uint4* db = (const uint4*)(dmin + N);    // dist2 as uint4
    for (int i = t; i < chunk; i += RBLK) {
        uint4 v1 = da[base + i], v2 = db[base + i];
        s1 += sqrtf(__uint_as_float(v1.x)) + sqrtf(__uint_as_float(v1.y))
            + sqrtf(__uint_as_float(v1.z)) + sqrtf(__uint_as_float(v1.w));
        s2 += sqrtf(__uint_as_float(v2.x)) + sqrtf(__uint_as_float(v2.y))
            + sqrtf(__uint_as_float(v2.z)) + sqrtf(__uint_as_float(v2.w));
    }
    #pragma unroll
    for (int off = 32; off > 0; off >>= 1) {
        s1 += __shfl_down(s1, off, 64);
        s2 += __shfl_down(s2, off, 64);
    }
    int wid = t >> 6, lane = t & 63;
    if (lane == 0) { sh1[wid] = s1; sh2[wid] = s2; }
    __syncthreads();
    if (t == 0) {
        float t1 = 0.0f, t2 = 0.0f;
        #pragma unroll
        for (int w = 0; w < RBLK / 64; ++w) { t1 += sh1[w]; t2 += sh2[w]; }
        bsum[blockIdx.x]         = t1;
        bsum[RGRID + blockIdx.x] = t2;
    }
}

// ----------------------------------------------------------------- final ----
__global__ void chamfer_final_kernel(const float* __restrict__ bsum,
        const int* __restrict__ curp, const int* __restrict__ subp,
        float* __restrict__ out) {
    if (threadIdx.x != 0) return;
    float s1 = 0.0f, s2 = 0.0f;
    #pragma unroll
    for (int b = 0; b < RGRID; ++b) { s1 += bsum[b]; s2 += bsum[RGRID + b]; }
    int e = curp[0] / subp[0];
    double scale = 10.0 / pow(0.99, (double)e);
    out[0] = (float)((((double)s1 + (double)s2) / (double)N) * 0.5 * scale);
}

// ---------------------------------------------------------------- launch ----
extern "C" void kernel_launch(void* const* d_in, const int* in_sizes, int n_in,
                              void* d_out, int out_size, void* d_ws, size_t ws_size,
                              hipStream_t stream) {
    const float* target = (const float*)d_in[0];   // (1, 8192, 3) f32
    const float* output = (const float*)d_in[1];   // (1, 8192, 3) f32
    const int*   curp   = (const int*)d_in[2];
    const int*   subp   = (const int*)d_in[3];
    float* out = (float*)d_out;

    // ws: float4 P[2N] (256KB) | uint dmin[2N] (64KB) | float bsum[16]
    float4*   P    = (float4*)d_ws;
    unsigned* dmin = (unsigned*)(P + 2 * N);
    float*    bsum = (float*)(dmin + 2 * N);

    chamfer_prep_kernel<<<2 * N / BLK, BLK, 0, stream>>>(target, output, P, dmin);
    chamfer_dist_kernel<<<GRID, BLK, 0, stream>>>(P, dmin);
    chamfer_reduce_kernel<<<RGRID, RBLK, 0, stream>>>(dmin, bsum);
    chamfer_final_kernel<<<1, 64, 0, stream>>>(bsum, curp, subp, out);
}

// Round 24
// 22.899 us; speedup vs baseline: 1.0251x; 1.0251x over previous
//
#include <hip/hip_runtime.h>
#include <math.h>

#define N      8192
#define BLK    256
#define RPT    8                    // resident b-points per lane
#define G      (RPT / 2)            // packed pair-groups per lane
#define BPW    (64 * RPT)           // 512 b-points per wave
#define NB     (N / BPW)            // 16 b-groups
#define NA     (N / 64)             // 128 a-tiles
#define GRID   ((NB * NA) / 4)      // 512 blocks of 4 waves
#define RBLK   1024
#define RGRID  8                    // widened reduce: 8 blocks

typedef float v2f __attribute__((ext_vector_type(2)));

// Full-wave rotate-by-1 on the VALU pipe (DPP wave_ror:1, ctrl 0x13C).
__device__ __forceinline__ float rot1(float x) {
    return __int_as_float(__builtin_amdgcn_mov_dpp(
        __float_as_int(x), 0x13C, 0xF, 0xF, false));
}

// ---------------------------------------------------------------- dist ----
// R22 structure (best: 22.73us) with the PREP KERNEL REMOVED: each wave
// packs its own points from the raw inputs (12B/point, lane-contiguous ->
// coalesced) and computes |p|^2 in-register (~30 one-off VALU ops). This
// kills one launch+gap and the P-buffer write/L2-flush/re-read round-trip.
// dmin is pre-set to +inf bits by hipMemsetD32Async (graph-native memset).
// DPP systolic ring: lane holds 8 B-points; A-packet {-2x,-2y,-2z,a2,
// runmin} rotates through 64 lanes; each pair computed ONCE serving BOTH
// directions. Col-mins pre-combined in LDS across the block's 4 waves
// (shared bt) -> one global commit per b-point per block.
__global__ __launch_bounds__(BLK) void chamfer_dist_kernel(
        const float* __restrict__ tgt, const float* __restrict__ outp,
        unsigned* __restrict__ dmin) {
    __shared__ unsigned cm[BPW];               // block-combined col-mins

    int tid  = (int)threadIdx.x;
    int lane = tid & 63;
    int W    = (int)blockIdx.x * 4 + (tid >> 6);   // global wave id
    int bt   = W >> 7;                             // b-group (shared by block)
    int at   = W & (NA - 1);                       // a-tile  (per wave)

    cm[tid]       = 0x7F800000u;
    cm[tid + 256] = 0x7F800000u;

    // resident B-points (output cloud), packed on the fly as point-pairs
    v2f bx2[G], by2[G], bz2[G], b22[G], ca2[G];
    #pragma unroll
    for (int g = 0; g < G; ++g) {
        int j0 = bt * BPW + (2 * g)     * 64 + lane;
        int j1 = bt * BPW + (2 * g + 1) * 64 + lane;
        float ux = outp[3 * j0 + 0], uy = outp[3 * j0 + 1], uz = outp[3 * j0 + 2];
        float vx = outp[3 * j1 + 0], vy = outp[3 * j1 + 1], vz = outp[3 * j1 + 2];
        bx2[g] = (v2f){ux, vx};
        by2[g] = (v2f){uy, vy};
        bz2[g] = (v2f){uz, vz};
        b22[g] = (v2f){fmaf(ux, ux, fmaf(uy, uy, uz * uz)),
                       fmaf(vx, vx, fmaf(vy, vy, vz * vz))};
        ca2[g] = (v2f){__builtin_inff(), __builtin_inff()};
    }

    // own A-packet (target cloud), packed on the fly
    int ia = at * 64 + lane;
    float axr = tgt[3 * ia + 0], ayr = tgt[3 * ia + 1], azr = tgt[3 * ia + 2];
    float px = -2.0f * axr;
    float py = -2.0f * ayr;
    float pz = -2.0f * azr;
    float pw = fmaf(axr, axr, fmaf(ayr, ayr, azr * azr));  // a^2
    float pr = __builtin_inff();          // traveling row-min (d^2)

    __syncthreads();                      // cm initialized

    for (int s = 0; s < 64; ++s) {
        v2f px2 = {px, px}, py2 = {py, py}, pz2 = {pz, pz}, pw2 = {pw, pw};
        #pragma unroll
        for (int g = 0; g < G; ++g) {
            v2f t = __builtin_elementwise_fma(pz2, bz2[g], b22[g] + pw2);
            t     = __builtin_elementwise_fma(py2, by2[g], t);
            t     = __builtin_elementwise_fma(px2, bx2[g], t);   // full d^2
            pr     = fminf(fminf(pr, t.x), t.y);                 // v_min3
            ca2[g] = __builtin_elementwise_min(ca2[g], t);
        }
        px = rot1(px);
        py = rot1(py);
        pz = rot1(pz);
        pw = rot1(pw);
        pr = rot1(pr);
    }

    // packet home after 64 rotations: commit row-min (per-wave a-tile)
    atomicMin(&dmin[at * 64 + lane], __float_as_uint(fmaxf(pr, 0.0f)));

    // col-mins: LDS pre-combine across the block's 4 waves, then ONE
    // global commit per b-point per block.
    #pragma unroll
    for (int g = 0; g < G; ++g) {
        atomicMin(&cm[(2 * g)     * 64 + lane],
                  __float_as_uint(fmaxf(ca2[g].x, 0.0f)));
        atomicMin(&cm[(2 * g + 1) * 64 + lane],
                  __float_as_uint(fmaxf(ca2[g].y, 0.0f)));
    }
    __syncthreads();
    atomicMin(&dmin[N + bt * BPW + tid],       cm[tid]);
    atomicMin(&dmin[N + bt * BPW + tid + 256], cm[tid + 256]);
}

// -------------------------------------------------------------- reduce ----
// 8 blocks x 1024 threads, each covering 1/8 of both dmin arrays.
__global__ __launch_bounds__(RBLK) void chamfer_reduce_kernel(
        const unsigned* __restrict__ dmin, float* __restrict__ bsum) {
    __shared__ float sh1[RBLK / 64], sh2[RBLK / 64];
    int t = (int)threadIdx.x;
    int chunk = N / 4 / RGRID;                     // uint4 elems per block
    int base = (int)blockIdx.x * chunk;
    float s1 = 0.0f, s2 = 0.0f;
    const uint4* da = (const uint4*)dmin;          // dist1 as uint4
    const uint4* db = (const uint4*)(dmin + N);    // dist2 as uint4
    for (int i = t; i < chunk; i += RBLK) {
        uint4 v1 = da[base + i], v2 = db[base + i];
        s1 += sqrtf(__uint_as_float(v1.x)) + sqrtf(__uint_as_float(v1.y))
            + sqrtf(__uint_as_float(v1.z)) + sqrtf(__uint_as_float(v1.w));
        s2 += sqrtf(__uint_as_float(v2.x)) + sqrtf(__uint_as_float(v2.y))
            + sqrtf(__uint_as_float(v2.z)) + sqrtf(__uint_as_float(v2.w));
    }
    #pragma unroll
    for (int off = 32; off > 0; off >>= 1) {
        s1 += __shfl_down(s1, off, 64);
        s2 += __shfl_down(s2, off, 64);
    }
    int wid = t >> 6, lane = t & 63;
    if (lane == 0) { sh1[wid] = s1; sh2[wid] = s2; }
    __syncthreads();
    if (t == 0) {
        float t1 = 0.0f, t2 = 0.0f;
        #pragma unroll
        for (int w = 0; w < RBLK / 64; ++w) { t1 += sh1[w]; t2 += sh2[w]; }
        bsum[blockIdx.x]         = t1;
        bsum[RGRID + blockIdx.x] = t2;
    }
}

// ----------------------------------------------------------------- final ----
__global__ void chamfer_final_kernel(const float* __restrict__ bsum,
        const int* __restrict__ curp, const int* __restrict__ subp,
        float* __restrict__ out) {
    if (threadIdx.x != 0) return;
    float s1 = 0.0f, s2 = 0.0f;
    #pragma unroll
    for (int b = 0; b < RGRID; ++b) { s1 += bsum[b]; s2 += bsum[RGRID + b]; }
    int e = curp[0] / subp[0];
    double scale = 10.0 / pow(0.99, (double)e);
    out[0] = (float)((((double)s1 + (double)s2) / (double)N) * 0.5 * scale);
}

// ---------------------------------------------------------------- launch ----
extern "C" void kernel_launch(void* const* d_in, const int* in_sizes, int n_in,
                              void* d_out, int out_size, void* d_ws, size_t ws_size,
                              hipStream_t stream) {
    const float* target = (const float*)d_in[0];   // (1, 8192, 3) f32
    const float* output = (const float*)d_in[1];   // (1, 8192, 3) f32
    const int*   curp   = (const int*)d_in[2];
    const int*   subp   = (const int*)d_in[3];
    float* out = (float*)d_out;

    // ws: uint dmin[2N] (64KB) | float bsum[16]
    unsigned* dmin = (unsigned*)d_ws;
    float*    bsum = (float*)(dmin + 2 * N);

    // graph-native 32-bit memset: dmin = +inf bits (no init kernel needed)
    hipMemsetD32Async((hipDeviceptr_t)dmin, 0x7F800000, 2 * N, stream);
    chamfer_dist_kernel<<<GRID, BLK, 0, stream>>>(target, output, dmin);
    chamfer_reduce_kernel<<<RGRID, RBLK, 0, stream>>>(dmin, bsum);
    chamfer_final_kernel<<<1, 64, 0, stream>>>(bsum, curp, subp, out);
}

// Round 25
// 22.573 us; speedup vs baseline: 1.0400x; 1.0145x over previous
//
#include <hip/hip_runtime.h>
#include <math.h>

#define N      8192
#define BLK    256
#define RPT    8                    // resident b-points per lane
#define G      (RPT / 2)            // packed pair-groups per lane
#define BPW    (64 * RPT)           // 512 b-points per wave
#define NB     (N / BPW)            // 16 b-groups
#define NA     (N / 64)             // 128 a-tiles
#define GRID   ((NB * NA) / 4)      // 512 blocks of 4 waves
#define RBLK   1024
#define RGRID  8                    // widened reduce: 8 blocks

typedef float v2f __attribute__((ext_vector_type(2)));

// Full-wave rotate-by-1 on the VALU pipe (DPP wave_ror:1, ctrl 0x13C).
__device__ __forceinline__ float rot1(float x) {
    return __int_as_float(__builtin_amdgcn_mov_dpp(
        __float_as_int(x), 0x13C, 0xF, 0xF, false));
}

__device__ __forceinline__ float min3f(float a, float b, float c) {
    return fminf(fminf(a, b), c);   // -> v_min3_f32
}

// ---------------------------------------------------- precompute + init ----
__global__ __launch_bounds__(BLK) void chamfer_prep_kernel(
        const float* __restrict__ tgt, const float* __restrict__ outp,
        float4* __restrict__ P, unsigned* __restrict__ dmin) {
    int i = blockIdx.x * BLK + (int)threadIdx.x;   // 0 .. 2N-1
    const float* src = (i < N) ? tgt : outp;
    int k = (i < N) ? i : (i - N);
    float x = src[3 * k + 0];
    float y = src[3 * k + 1];
    float z = src[3 * k + 2];
    P[i] = make_float4(x, y, z, fmaf(x, x, fmaf(y, y, z * z)));
    dmin[i] = 0x7F800000u;  // +inf
}

// ---------------------------------------------------------------- dist ----
// R22 structure (best: 22.73us) with ONE change: the per-step traveling
// row-min is a DEPTH-2 TREE of v_min3 (u1,u2 independent of pr; u3 folds
// pr) instead of a 4-deep serial min3 chain — same op count, loop-carried
// dependency depth halved (~20 -> ~10 cyc/step), relevant at 2 waves/SIMD.
__global__ __launch_bounds__(BLK) void chamfer_dist_kernel(
        const float4* __restrict__ P, unsigned* __restrict__ dmin) {
    __shared__ unsigned cm[BPW];               // block-combined col-mins

    int tid  = (int)threadIdx.x;
    int lane = tid & 63;
    int W    = (int)blockIdx.x * 4 + (tid >> 6);   // global wave id
    int bt   = W >> 7;                             // b-group (shared by block)
    int at   = W & (NA - 1);                       // a-tile  (per wave)

    cm[tid]       = 0x7F800000u;
    cm[tid + 256] = 0x7F800000u;

    // resident B-points (output cloud), packed as point-pairs
    v2f bx2[G], by2[G], bz2[G], b22[G], ca2[G];
    #pragma unroll
    for (int g = 0; g < G; ++g) {
        float4 u = P[N + bt * BPW + (2 * g)     * 64 + lane];
        float4 v = P[N + bt * BPW + (2 * g + 1) * 64 + lane];
        bx2[g] = (v2f){u.x, v.x};
        by2[g] = (v2f){u.y, v.y};
        bz2[g] = (v2f){u.z, v.z};
        b22[g] = (v2f){u.w, v.w};
        ca2[g] = (v2f){__builtin_inff(), __builtin_inff()};
    }

    // own A-packet (target cloud)
    float4 a = P[at * 64 + lane];
    float px = -2.0f * a.x;
    float py = -2.0f * a.y;
    float pz = -2.0f * a.z;
    float pw = a.w;                       // a^2
    float pr = __builtin_inff();          // traveling row-min (d^2)

    __syncthreads();                      // cm initialized

    for (int s = 0; s < 64; ++s) {
        v2f px2 = {px, px}, py2 = {py, py}, pz2 = {pz, pz}, pw2 = {pw, pw};
        v2f t0, t1, t2, t3;
        {
            t0 = __builtin_elementwise_fma(pz2, bz2[0], b22[0] + pw2);
            t0 = __builtin_elementwise_fma(py2, by2[0], t0);
            t0 = __builtin_elementwise_fma(px2, bx2[0], t0);
            ca2[0] = __builtin_elementwise_min(ca2[0], t0);
            t1 = __builtin_elementwise_fma(pz2, bz2[1], b22[1] + pw2);
            t1 = __builtin_elementwise_fma(py2, by2[1], t1);
            t1 = __builtin_elementwise_fma(px2, bx2[1], t1);
            ca2[1] = __builtin_elementwise_min(ca2[1], t1);
            t2 = __builtin_elementwise_fma(pz2, bz2[2], b22[2] + pw2);
            t2 = __builtin_elementwise_fma(py2, by2[2], t2);
            t2 = __builtin_elementwise_fma(px2, bx2[2], t2);
            ca2[2] = __builtin_elementwise_min(ca2[2], t2);
            t3 = __builtin_elementwise_fma(pz2, bz2[3], b22[3] + pw2);
            t3 = __builtin_elementwise_fma(py2, by2[3], t3);
            t3 = __builtin_elementwise_fma(px2, bx2[3], t3);
            ca2[3] = __builtin_elementwise_min(ca2[3], t3);
        }
        // depth-2 min3 tree (u1,u2 independent of pr)
        float u1 = min3f(t0.x, t0.y, t1.x);
        float u2 = min3f(t1.y, t2.x, t2.y);
        float u3 = min3f(t3.x, t3.y, pr);
        pr = min3f(u1, u2, u3);

        px = rot1(px);
        py = rot1(py);
        pz = rot1(pz);
        pw = rot1(pw);
        pr = rot1(pr);
    }

    // packet home after 64 rotations: commit row-min (per-wave a-tile)
    atomicMin(&dmin[at * 64 + lane], __float_as_uint(fmaxf(pr, 0.0f)));

    // col-mins: LDS pre-combine across the block's 4 waves, then ONE
    // global commit per b-point per block.
    #pragma unroll
    for (int g = 0; g < G; ++g) {
        atomicMin(&cm[(2 * g)     * 64 + lane],
                  __float_as_uint(fmaxf(ca2[g].x, 0.0f)));
        atomicMin(&cm[(2 * g + 1) * 64 + lane],
                  __float_as_uint(fmaxf(ca2[g].y, 0.0f)));
    }
    __syncthreads();
    atomicMin(&dmin[N + bt * BPW + tid],       cm[tid]);
    atomicMin(&dmin[N + bt * BPW + tid + 256], cm[tid + 256]);
}

// -------------------------------------------------------------- reduce ----
// 8 blocks x 1024 threads, each covering 1/8 of both dmin arrays.
__global__ __launch_bounds__(RBLK) void chamfer_reduce_kernel(
        const unsigned* __restrict__ dmin, float* __restrict__ bsum) {
    __shared__ float sh1[RBLK / 64], sh2[RBLK / 64];
    int t = (int)threadIdx.x;
    int chunk = N / 4 / RGRID;                     // uint4 elems per block
    int base = (int)blockIdx.x * chunk;
    float s1 = 0.0f, s2 = 0.0f;
    const uint4* da = (const uint4*)dmin;          // dist1 as uint4
    const uint4* db = (const uint4*)(dmin + N);    // dist2 as uint4
    for (int i = t; i < chunk; i += RBLK) {
        uint4 v1 = da[base + i], v2 = db[base + i];
        s1 += sqrtf(__uint_as_float(v1.x)) + sqrtf(__uint_as_float(v1.y))
            + sqrtf(__uint_as_float(v1.z)) + sqrtf(__uint_as_float(v1.w));
        s2 += sqrtf(__uint_as_float(v2.x)) + sqrtf(__uint_as_float(v2.y))
            + sqrtf(__uint_as_float(v2.z)) + sqrtf(__uint_as_float(v2.w));
    }
    #pragma unroll
    for (int off = 32; off > 0; off >>= 1) {
        s1 += __shfl_down(s1, off, 64);
        s2 += __shfl_down(s2, off, 64);
    }
    int wid = t >> 6, lane = t & 63;
    if (lane == 0) { sh1[wid] = s1; sh2[wid] = s2; }
    __syncthreads();
    if (t == 0) {
        float t1 = 0.0f, t2 = 0.0f;
        #pragma unroll
        for (int w = 0; w < RBLK / 64; ++w) { t1 += sh1[w]; t2 += sh2[w]; }
        bsum[blockIdx.x]         = t1;
        bsum[RGRID + blockIdx.x] = t2;
    }
}

// ----------------------------------------------------------------- final ----
__global__ void chamfer_final_kernel(const float* __restrict__ bsum,
        const int* __restrict__ curp, const int* __restrict__ subp,
        float* __restrict__ out) {
    if (threadIdx.x != 0) return;
    float s1 = 0.0f, s2 = 0.0f;
    #pragma unroll
    for (int b = 0; b < RGRID; ++b) { s1 += bsum[b]; s2 += bsum[RGRID + b]; }
    int e = curp[0] / subp[0];
    double scale = 10.0 / pow(0.99, (double)e);
    out[0] = (float)((((double)s1 + (double)s2) / (double)N) * 0.5 * scale);
}

// ---------------------------------------------------------------- launch ----
extern "C" void kernel_launch(void* const* d_in, const int* in_sizes, int n_in,
                              void* d_out, int out_size, void* d_ws, size_t ws_size,
                              hipStream_t stream) {
    const float* target = (const float*)d_in[0];   // (1, 8192, 3) f32
    const float* output = (const float*)d_in[1];   // (1, 8192, 3) f32
    const int*   curp   = (const int*)d_in[2];
    const int*   subp   = (const int*)d_in[3];
    float* out = (float*)d_out;

    // ws: float4 P[2N] (256KB) | uint dmin[2N] (64KB) | float bsum[16]
    float4*   P    = (float4*)d_ws;
    unsigned* dmin = (unsigned*)(P + 2 * N);
    float*    bsum = (float*)(dmin + 2 * N);

    chamfer_prep_kernel<<<2 * N / BLK, BLK, 0, stream>>>(target, output, P, dmin);
    chamfer_dist_kernel<<<GRID, BLK, 0, stream>>>(P, dmin);
    chamfer_reduce_kernel<<<RGRID, RBLK, 0, stream>>>(dmin, bsum);
    chamfer_final_kernel<<<1, 64, 0, stream>>>(bsum, curp, subp, out);
}